// Round 1
// 1307.710 us; speedup vs baseline: 1.2628x; 1.2628x over previous
//
#include <hip/hip_runtime.h>
#include <stdint.h>

// Problem constants
#define LL 128
#define BB 4096
#define DD 300
#define DP 320              // K padded to multiple of 32
#define SROW 328            // LDS row stride in bf16 elements (bank advance = 4 dwords)

typedef __attribute__((ext_vector_type(8))) short short8;
typedef __attribute__((ext_vector_type(4))) float f32x4;

static constexpr int S16_ELEMS = 129 * SROW;
// S16 (bf16) + q1s/q2s/w0s/w1s/w2s (5 x 128 f32)
static constexpr int SMEM_BYTES = S16_ELEMS * 2 + 128 * 5 * 4;

__device__ __forceinline__ unsigned short f2bf(float f) {
    unsigned int u = __builtin_bit_cast(unsigned int, f);
    u = (u + 0x7fffu + ((u >> 16) & 1u)) >> 16;   // RNE
    return (unsigned short)u;
}
__device__ __forceinline__ float bf2f(unsigned short h) {
    unsigned int u = ((unsigned int)h) << 16;
    return __builtin_bit_cast(float, u);
}

// ---- prep: Wb[320][320] = bf16( 0.5*(W + W^T) ), zero padded ----
__global__ void prep_w_kernel(const float* __restrict__ W, unsigned short* __restrict__ Wb) {
    int i = blockIdx.x * 256 + threadIdx.x;
    if (i >= DP * DP) return;
    int r = i / DP, c = i % DP;
    float v = 0.0f;
    if (r < DD && c < DD) v = 0.5f * (W[r * DD + c] + W[c * DD + r]);
    Wb[i] = f2bf(v);
}

// ---- fused: scores via MFMA (Y^T = Wsym * S^T) + parallel softmax/combine ----
__global__ __launch_bounds__(512) void fused_kernel(
        const float* __restrict__ sent, const int* __restrict__ sizes,
        const unsigned short* __restrict__ Wb, float* __restrict__ out) {
    extern __shared__ char smem[];
    unsigned short* S16 = (unsigned short*)smem;
    float* q1s = (float*)(smem + S16_ELEMS * 2);
    float* q2s = q1s + 128;
    float* w0s = q2s + 128;
    float* w1s = w0s + 128;
    float* w2s = w1s + 128;

    const int b = blockIdx.x;
    const int t = threadIdx.x;

    // ---------------- stage sentence[:, b, :] as bf16 into LDS ----------------
    for (int idx = t; idx < 128 * 75; idx += 512) {
        int row = idx / 75, c4 = idx % 75;
        const float4 v = ((const float4*)(sent + ((size_t)row * BB + b) * DD))[c4];
        ushort4 h;
        h.x = f2bf(v.x); h.y = f2bf(v.y); h.z = f2bf(v.z); h.w = f2bf(v.w);
        *(ushort4*)&S16[row * SROW + c4 * 4] = h;
    }
    // zero pad cols 300..327 for all 129 rows
    for (int r = t; r < 129; r += 512) {
        #pragma unroll
        for (int c = 300; c < SROW; c += 4) {
            ushort4 z; z.x = 0; z.y = 0; z.z = 0; z.w = 0;
            *(ushort4*)&S16[r * SROW + c] = z;
        }
    }
    // zero row 128 (cols 0..299)
    for (int c4 = t; c4 < 75; c4 += 512) {
        ushort4 z; z.x = 0; z.y = 0; z.z = 0; z.w = 0;
        *(ushort4*)&S16[128 * SROW + c4 * 4] = z;
    }
    // zero score accumulators (q1s[128] + q2s[128] contiguous)
    if (t < 256) q1s[t] = 0.0f;
    __syncthreads();

    // ---------------- MFMA: Yt = Wsym * S^T (tiles: rows d, cols l) ----------------
    const int lane = t & 63;
    const int wave = t >> 6;       // 0..7
    const int mw = wave & 3;       // 0..3 : d-partition, md = 5*mw + i
    const int nw2 = wave >> 2;     // 0..1 : l-partition, nl = 4*nw2 + j
    const int lo = lane & 15;
    const int quad = lane >> 4;

    f32x4 acc[5][4];
    #pragma unroll
    for (int i = 0; i < 5; i++)
        #pragma unroll
        for (int j = 0; j < 4; j++)
            acc[i][j] = (f32x4){0.f, 0.f, 0.f, 0.f};

    #pragma unroll
    for (int kc = 0; kc < 10; kc++) {
        short8 Af[5], Bf[4];
        #pragma unroll
        for (int i = 0; i < 5; i++)
            Af[i] = *(const short8*)&Wb[(16 * (5 * mw + i) + lo) * DP + kc * 32 + quad * 8];
        #pragma unroll
        for (int j = 0; j < 4; j++)
            Bf[j] = *(const short8*)&S16[(16 * (4 * nw2 + j) + lo) * SROW + kc * 32 + quad * 8];
        #pragma unroll
        for (int i = 0; i < 5; i++)
            #pragma unroll
            for (int j = 0; j < 4; j++)
                acc[i][j] = __builtin_amdgcn_mfma_f32_16x16x32_bf16(Af[i], Bf[j], acc[i][j], 0, 0, 0);
    }

    // ---------------- dots (vectorized): q1[l] += Yt[d,l]*S[l,d]; q2[l] += Yt[d,l]*S[l+1,d]
    // lane holds col l = 16*nl + lo, rows d = 16*md + quad*4 + r  -> S reads are ushort4
    float q1v[4] = {0.f, 0.f, 0.f, 0.f};
    float q2v[4] = {0.f, 0.f, 0.f, 0.f};
    #pragma unroll
    for (int i = 0; i < 5; i++) {
        const int d0 = 16 * (5 * mw + i) + quad * 4;
        #pragma unroll
        for (int j = 0; j < 4; j++) {
            const int l = 16 * (4 * nw2 + j) + lo;
            const ushort4 s1 = *(const ushort4*)&S16[l * SROW + d0];
            const ushort4 s2 = *(const ushort4*)&S16[(l + 1) * SROW + d0];
            const f32x4 a = acc[i][j];
            q1v[j] += a[0] * bf2f(s1.x) + a[1] * bf2f(s1.y) + a[2] * bf2f(s1.z) + a[3] * bf2f(s1.w);
            q2v[j] += a[0] * bf2f(s2.x) + a[1] * bf2f(s2.y) + a[2] * bf2f(s2.z) + a[3] * bf2f(s2.w);
        }
    }
    // reduce across the 4 quads (lanes lo, lo+16, lo+32, lo+48), then 4-way atomic across mw-waves
    #pragma unroll
    for (int j = 0; j < 4; j++) {
        float v1 = q1v[j], v2 = q2v[j];
        v1 += __shfl_xor(v1, 16); v1 += __shfl_xor(v1, 32);
        v2 += __shfl_xor(v2, 16); v2 += __shfl_xor(v2, 32);
        if (quad == 0) {
            const int l = 16 * (4 * nw2 + j) + lo;
            atomicAdd(&q1s[l], v1);
            atomicAdd(&q2s[l], v2);
        }
    }
    __syncthreads();

    // ---------------- softmax weights, once per l ----------------
    const int sz = sizes[b];
    if (t < 128) {
        const int l = t;
        const float inv_d = 1.0f / 300.0f;
        const float NEG_INF = -__builtin_inff();
        const float a1 = q1s[l] * inv_d;
        const float a0 = (l >= 1 && l < sz) ? q2s[l - 1] * inv_d : NEG_INF;
        const float a2 = (l < LL - 1 && l < sz - 1) ? q2s[l] * inv_d : NEG_INF;
        const float mx = fmaxf(a1, fmaxf(a0, a2));
        const float e0 = __expf(a0 - mx);
        const float e1 = __expf(a1 - mx);
        const float e2 = __expf(a2 - mx);
        const float inv = 1.0f / (e0 + e1 + e2);
        w0s[l] = e0 * inv;
        w1s[l] = e1 * inv;
        w2s[l] = e2 * inv;
    }
    __syncthreads();

    // ---------------- combine: all 512 threads over (l, d/4), float4 stores ----------------
    for (int idx = t; idx < 128 * 75; idx += 512) {
        const int l = idx / 75;
        const int d = (idx % 75) * 4;
        const float W0 = w0s[l], W1 = w1s[l], W2 = w2s[l];
        const int lp = (l == 0) ? 0 : l - 1;            // W0 == 0 at l == 0
        const ushort4 sp = *(const ushort4*)&S16[lp * SROW + d];
        const ushort4 sc = *(const ushort4*)&S16[l * SROW + d];
        const ushort4 sn = *(const ushort4*)&S16[(l + 1) * SROW + d];  // row 128 zeroed
        float4 o;
        o.x = W1 * bf2f(sc.x) + W0 * bf2f(sp.x) + W2 * bf2f(sn.x);
        o.y = W1 * bf2f(sc.y) + W0 * bf2f(sp.y) + W2 * bf2f(sn.y);
        o.z = W1 * bf2f(sc.z) + W0 * bf2f(sp.z) + W2 * bf2f(sn.z);
        o.w = W1 * bf2f(sc.w) + W0 * bf2f(sp.w) + W2 * bf2f(sn.w);
        *(float4*)&out[((size_t)l * BB + b) * DD + d] = o;
    }
}

extern "C" void kernel_launch(void* const* d_in, const int* in_sizes, int n_in,
                              void* d_out, int out_size, void* d_ws, size_t ws_size,
                              hipStream_t stream) {
    const float* sent = (const float*)d_in[0];
    const int* sizes  = (const int*)d_in[1];
    const float* W    = (const float*)d_in[2];
    float* out        = (float*)d_out;
    unsigned short* Wb = (unsigned short*)d_ws;   // 320*320*2 = 204800 B

    prep_w_kernel<<<(DP * DP + 255) / 256, 256, 0, stream>>>(W, Wb);

    hipFuncSetAttribute(reinterpret_cast<const void*>(fused_kernel),
                        hipFuncAttributeMaxDynamicSharedMemorySize, SMEM_BYTES);
    fused_kernel<<<BB, 512, SMEM_BYTES, stream>>>(sent, sizes, Wb, out);
}